// Round 1
// baseline (232.357 us; speedup 1.0000x reference)
//
#include <hip/hip_runtime.h>

// TripletLoss batch-hard mining, N=8192, D=256, 64 classes, margin 0.3.
// Strategy: fused bf16-MFMA X@X^T with per-row hardest-pos (max d^2 over same
// label) / hardest-neg (min d^2 over diff label) mining; sqrt once per anchor.

#define N_PTS 8192
#define DIM   256
#define MARGIN 0.3f

typedef __attribute__((ext_vector_type(8))) short bf16x8;
typedef __attribute__((ext_vector_type(4))) float f32x4;

__device__ __forceinline__ unsigned short f2bf(float f) {
    unsigned u = __float_as_uint(f);
    u += 0x7FFFu + ((u >> 16) & 1u);   // round-to-nearest-even
    return (unsigned short)(u >> 16);
}

// ---------------------------------------------------------------- prep ----
// wave-per-row: lane l handles cols [4l,4l+4). Emits bf16 copy, row sq-norm,
// class histogram, and initializes hp2 (0.0f bits) / hn2 (+inf bits).
__global__ void prep_kernel(const float* __restrict__ X,
                            const int* __restrict__ labels,
                            unsigned short* __restrict__ Xb,
                            float* __restrict__ sq,
                            unsigned* __restrict__ hp2,
                            unsigned* __restrict__ hn2,
                            int* __restrict__ hist) {
    int t = blockIdx.x * 256 + threadIdx.x;     // t = row*64 + lane
    int row = t >> 6;
    int lane = t & 63;
    float4 v = reinterpret_cast<const float4*>(X)[t];
    ushort4 b4;
    b4.x = f2bf(v.x); b4.y = f2bf(v.y); b4.z = f2bf(v.z); b4.w = f2bf(v.w);
    reinterpret_cast<ushort4*>(Xb)[t] = b4;
    float p = v.x * v.x + v.y * v.y + v.z * v.z + v.w * v.w;
    #pragma unroll
    for (int m = 1; m < 64; m <<= 1) p += __shfl_xor(p, m, 64);
    if (lane == 0) {
        sq[row]  = p;
        hp2[row] = 0u;           // 0.0f : "no positive with d2>0 yet"
        hn2[row] = 0x7F800000u;  // +inf : "no negative yet"
        atomicAdd(&hist[labels[row]], 1);
    }
}

// ---------------------------------------------------------------- mine ----
// 128x128 output tile per block, 4 waves in 2x2 (64x64 each, acc[4][4] of
// 16x16x32 bf16 MFMA). BK=64, K=256 -> 4 staging iterations via
// global_load_lds width=16. LDS chunk XOR-swizzle (chunk' = chunk ^ (row&7),
// rows are 64 bf16 = 8 chunks of 16B) makes frag ds_read_b128 conflict-free;
// swizzle applied on the per-lane GLOBAL source address (rule: linear LDS
// dest for global_load_lds) and on the read offset.
__launch_bounds__(256, 2)
__global__ void mine_kernel(const unsigned short* __restrict__ Xb,
                            const float* __restrict__ sq,
                            const int* __restrict__ labels,
                            unsigned* __restrict__ hp2,
                            unsigned* __restrict__ hn2) {
    __shared__ unsigned short As[128 * 64];
    __shared__ unsigned short Bs[128 * 64];

    int blk = blockIdx.x;
    // XCD-aware swizzle: 4096 blocks, 8 XCDs -> contiguous 512-block chunks.
    int swz = (blk & 7) * 512 + (blk >> 3);
    int bi = swz >> 6;
    int bj = swz & 63;
    int R0 = bi * 128, C0 = bj * 128;

    int tid = threadIdx.x;
    int w = tid >> 6;
    int l = tid & 63;
    int wr = w >> 1, wc = w & 1;

    // staging: chunk p = (w*256 + i*64) + lane; row = p>>3, stored slot c'=p&7
    // holds data kc = c' ^ (row&7). row&7 == l>>3 here, so kc_src is per-lane.
    int srow   = w * 32 + (l >> 3);        // + i*8
    int kc_src = (l & 7) ^ (l >> 3);

    f32x4 acc[4][4];
    #pragma unroll
    for (int m = 0; m < 4; ++m)
        #pragma unroll
        for (int n = 0; n < 4; ++n) acc[m][n] = (f32x4){0.f, 0.f, 0.f, 0.f};

    int arow = wr * 64 + (l & 15);   // + m*16 ; (row&7) == l&7
    int bcol = wc * 64 + (l & 15);   // + n*16
    int xorv = l & 7;
    int cbase = l >> 4;              // k-group of this lane

    for (int kt = 0; kt < 256; kt += 64) {
        #pragma unroll
        for (int i = 0; i < 4; ++i) {
            const unsigned short* ga =
                Xb + (size_t)(R0 + srow + i * 8) * DIM + kt + kc_src * 8;
            __builtin_amdgcn_global_load_lds(
                (const __attribute__((address_space(1))) void*)ga,
                (__attribute__((address_space(3))) void*)(As + (w * 256 + i * 64) * 8),
                16, 0, 0);
            const unsigned short* gb =
                Xb + (size_t)(C0 + srow + i * 8) * DIM + kt + kc_src * 8;
            __builtin_amdgcn_global_load_lds(
                (const __attribute__((address_space(1))) void*)gb,
                (__attribute__((address_space(3))) void*)(Bs + (w * 256 + i * 64) * 8),
                16, 0, 0);
        }
        __syncthreads();   // compiler drains vmcnt before s_barrier
        #pragma unroll
        for (int kk = 0; kk < 2; ++kk) {
            int c = ((kk * 4 + cbase) ^ xorv) * 8;
            bf16x8 a[4], b[4];
            #pragma unroll
            for (int m = 0; m < 4; ++m)
                a[m] = *reinterpret_cast<const bf16x8*>(&As[(arow + m * 16) * 64 + c]);
            #pragma unroll
            for (int n = 0; n < 4; ++n)
                b[n] = *reinterpret_cast<const bf16x8*>(&Bs[(bcol + n * 16) * 64 + c]);
            #pragma unroll
            for (int m = 0; m < 4; ++m)
                #pragma unroll
                for (int n = 0; n < 4; ++n)
                    acc[m][n] = __builtin_amdgcn_mfma_f32_16x16x32_bf16(
                        a[m], b[n], acc[m][n], 0, 0, 0);
        }
        __syncthreads();
    }

    // ---- fused mining epilogue ----
    // C/D layout (m89-verified): col = lane&15, row = (lane>>4)*4 + reg.
    int lc[4]; float sc[4];
    #pragma unroll
    for (int n = 0; n < 4; ++n) {
        int gc = C0 + wc * 64 + n * 16 + (l & 15);
        lc[n] = labels[gc];
        sc[n] = sq[gc];
    }
    const float INF = __int_as_float(0x7f800000);
    #pragma unroll
    for (int m = 0; m < 4; ++m) {
        int growb = R0 + wr * 64 + m * 16 + ((l >> 4) << 2);
        #pragma unroll
        for (int j = 0; j < 4; ++j) {
            int grow = growb + j;
            int lr = labels[grow];
            float sr = sq[grow];
            float hp = 0.f, hn = INF;
            #pragma unroll
            for (int n = 0; n < 4; ++n) {
                float d2 = fmaf(-2.f, acc[m][n][j], sr + sc[n]);
                d2 = fmaxf(d2, 0.f);
                bool same = (lr == lc[n]);
                hp = same ? fmaxf(hp, d2) : hp;   // hp>0 iff some pos d2>0
                hn = same ? hn : fminf(hn, d2);
            }
            #pragma unroll
            for (int s = 1; s < 16; s <<= 1) {    // reduce 16 col-lanes
                hp = fmaxf(hp, __shfl_xor(hp, s, 64));
                hn = fminf(hn, __shfl_xor(hn, s, 64));
            }
            if ((l & 15) == 0) {
                // d2 >= 0 -> float order == signed-int bit order
                atomicMax(reinterpret_cast<int*>(hp2) + grow, __float_as_int(hp));
                atomicMin(reinterpret_cast<int*>(hn2) + grow, __float_as_int(hn));
            }
        }
    }
}

// ------------------------------------------------------------ finalize ----
__global__ void finalize_kernel(const unsigned* __restrict__ hp2,
                                const unsigned* __restrict__ hn2,
                                const int* __restrict__ labels,
                                const int* __restrict__ hist,
                                float* __restrict__ out) {
    float s = 0.f, c = 0.f;
    for (int i = threadIdx.x; i < N_PTS; i += 256) {
        float hp = __uint_as_float(hp2[i]);
        float hn = __uint_as_float(hn2[i]);
        int h = hist[labels[i]];
        bool valid = (h > 1) && (h < N_PTS) && (hp > 0.f) && (hn < 3.0e38f);
        if (valid) {
            s += fmaxf(sqrtf(hp) - sqrtf(hn) + MARGIN, 0.f);
            c += 1.f;
        }
    }
    #pragma unroll
    for (int m = 1; m < 64; m <<= 1) {
        s += __shfl_xor(s, m, 64);
        c += __shfl_xor(c, m, 64);
    }
    __shared__ float ss[4], cc[4];
    int w = threadIdx.x >> 6, l = threadIdx.x & 63;
    if (l == 0) { ss[w] = s; cc[w] = c; }
    __syncthreads();
    if (threadIdx.x == 0) {
        float S = ss[0] + ss[1] + ss[2] + ss[3];
        float C = cc[0] + cc[1] + cc[2] + cc[3];
        out[0] = (C > 0.f) ? (S / C) : 0.f;
    }
}

// -------------------------------------------------------------- launch ----
extern "C" void kernel_launch(void* const* d_in, const int* in_sizes, int n_in,
                              void* d_out, int out_size, void* d_ws, size_t ws_size,
                              hipStream_t stream) {
    const float* X      = (const float*)d_in[0];
    const int*   labels = (const int*)d_in[1];
    float*       out    = (float*)d_out;

    char* ws = (char*)d_ws;
    unsigned short* Xb = (unsigned short*)ws;                       // 4 MB
    float*    sq  = (float*)(ws + (size_t)N_PTS * DIM * 2);
    unsigned* hp2 = (unsigned*)((char*)sq  + N_PTS * sizeof(float));
    unsigned* hn2 = (unsigned*)((char*)hp2 + N_PTS * sizeof(unsigned));
    int*      hist = (int*)((char*)hn2 + N_PTS * sizeof(unsigned));

    hipMemsetAsync(hist, 0, 64 * sizeof(int), stream);
    prep_kernel<<<N_PTS / 4, 256, 0, stream>>>(X, labels, Xb, sq, hp2, hn2, hist);
    mine_kernel<<<4096, 256, 0, stream>>>(Xb, sq, labels, hp2, hn2);
    finalize_kernel<<<1, 256, 0, stream>>>(hp2, hn2, labels, hist, out);
}

// Round 2
// 158.094 us; speedup vs baseline: 1.4697x; 1.4697x over previous
//
#include <hip/hip_runtime.h>

// TripletLoss batch-hard mining, N=8192, D=256, 64 classes, margin 0.3.
// R2: symmetric tiles (upper triangle only, row+col mining) + BK=128 staging
// (2 barrier pairs per block instead of 4) + global hist atomics removed.

#define N_PTS 8192
#define DIM   256
#define MARGIN 0.3f
#define NT    64          // 8192/128 tiles per dim
#define NPAIR 2080        // NT*(NT+1)/2 upper-triangle tiles

typedef __attribute__((ext_vector_type(8))) short bf16x8;
typedef __attribute__((ext_vector_type(4))) float f32x4;

__device__ __forceinline__ unsigned short f2bf(float f) {
    unsigned u = __float_as_uint(f);
    u += 0x7FFFu + ((u >> 16) & 1u);   // round-to-nearest-even
    return (unsigned short)(u >> 16);
}

// ---------------------------------------------------------------- prep ----
// wave-per-row: lane l handles cols [4l,4l+4). bf16 copy + row sq-norm +
// init hp2 (0.0f) / hn2 (+inf). No global atomics (hist moved to finalize).
__global__ void prep_kernel(const float* __restrict__ X,
                            unsigned short* __restrict__ Xb,
                            float* __restrict__ sq,
                            unsigned* __restrict__ hp2,
                            unsigned* __restrict__ hn2) {
    int t = blockIdx.x * 256 + threadIdx.x;     // t = row*64 + lane
    int row = t >> 6;
    int lane = t & 63;
    float4 v = reinterpret_cast<const float4*>(X)[t];
    ushort4 b4;
    b4.x = f2bf(v.x); b4.y = f2bf(v.y); b4.z = f2bf(v.z); b4.w = f2bf(v.w);
    reinterpret_cast<ushort4*>(Xb)[t] = b4;
    float p = v.x * v.x + v.y * v.y + v.z * v.z + v.w * v.w;
    #pragma unroll
    for (int m = 1; m < 64; m <<= 1) p += __shfl_xor(p, m, 64);
    if (lane == 0) {
        sq[row]  = p;
        hp2[row] = 0u;           // 0.0f : "no positive with d2>0 yet"
        hn2[row] = 0x7F800000u;  // +inf : "no negative yet"
    }
}

// ---------------------------------------------------------------- mine ----
// 128x128 tile, upper triangle only (bi<=bj). 4 waves 2x2, 64x64 each,
// acc[4][4] of 16x16x32 bf16 MFMA. BK=128: As/Bs [128][128] bf16 (32KB each,
// 64KB total -> 2 blocks/CU). Row layout: 16 chunks of 16B; XOR-swizzle
// slot = chunk ^ (row&15), applied on the per-lane GLOBAL source address
// (linear LDS dest for global_load_lds) and on the ds_read offset.
// Epilogue mines BOTH rows (anchors in bi-panel) and cols (anchors in
// bj-panel); max/min atomics are idempotent so diagonal blocks are safe.
__launch_bounds__(256, 2)
__global__ void mine_kernel(const unsigned short* __restrict__ Xb,
                            const float* __restrict__ sq,
                            const int* __restrict__ labels,
                            unsigned* __restrict__ hp2,
                            unsigned* __restrict__ hn2) {
    __shared__ unsigned short As[128 * 128];
    __shared__ unsigned short Bs[128 * 128];

    // XCD-aware swizzle: 2080 = 8*260, bijective contiguous chunks per XCD.
    int t = blockIdx.x;
    int swz = (t & 7) * (NPAIR / 8) + (t >> 3);
    // decode upper-triangle row-major: swz -> (bi, bj), bi <= bj
    int bi = 0, rem = swz;
    while (rem >= NT - bi) { rem -= NT - bi; ++bi; }
    int bj = bi + rem;
    int R0 = bi * 128, C0 = bj * 128;

    int tid = threadIdx.x;
    int w = tid >> 6;
    int l = tid & 63;
    int wr = w >> 1, wc = w & 1;
    int lsub = l & 15, lgrp = l >> 4;

    f32x4 acc[4][4];
    #pragma unroll
    for (int m = 0; m < 4; ++m)
        #pragma unroll
        for (int n = 0; n < 4; ++n) acc[m][n] = (f32x4){0.f, 0.f, 0.f, 0.f};

    for (int kt = 0; kt < DIM; kt += 128) {
        // stage 32KB+32KB: per wave 8 A-loads + 8 B-loads of 1KB.
        // linear chunk p = w*512 + i*64 + l; row = p>>4, slot = p&15 = l&15;
        // slot holds logical chunk kc = slot ^ (row&15).
        #pragma unroll
        for (int i = 0; i < 8; ++i) {
            int row = w * 32 + i * 4 + lgrp;
            int kc = lsub ^ (row & 15);
            const unsigned short* ga =
                Xb + (size_t)(R0 + row) * DIM + kt + kc * 8;
            __builtin_amdgcn_global_load_lds(
                (const __attribute__((address_space(1))) void*)ga,
                (__attribute__((address_space(3))) void*)(As + (w * 512 + i * 64) * 8),
                16, 0, 0);
            const unsigned short* gb =
                Xb + (size_t)(C0 + row) * DIM + kt + kc * 8;
            __builtin_amdgcn_global_load_lds(
                (const __attribute__((address_space(1))) void*)gb,
                (__attribute__((address_space(3))) void*)(Bs + (w * 512 + i * 64) * 8),
                16, 0, 0);
        }
        __syncthreads();
        #pragma unroll
        for (int kk = 0; kk < 4; ++kk) {
            int c = ((kk * 4 + lgrp) ^ lsub) * 8;   // physical 16B chunk * 8 shorts
            bf16x8 a[4], b[4];
            #pragma unroll
            for (int m = 0; m < 4; ++m)
                a[m] = *reinterpret_cast<const bf16x8*>(
                    &As[(wr * 64 + m * 16 + lsub) * 128 + c]);
            #pragma unroll
            for (int n = 0; n < 4; ++n)
                b[n] = *reinterpret_cast<const bf16x8*>(
                    &Bs[(wc * 64 + n * 16 + lsub) * 128 + c]);
            #pragma unroll
            for (int m = 0; m < 4; ++m)
                #pragma unroll
                for (int n = 0; n < 4; ++n)
                    acc[m][n] = __builtin_amdgcn_mfma_f32_16x16x32_bf16(
                        a[m], b[n], acc[m][n], 0, 0, 0);
        }
        __syncthreads();
    }

    // ---- fused mining epilogue (rows AND cols) ----
    // C/D layout: col = lane&15, row = (lane>>4)*4 + reg.
    int lc4[4]; float sc4[4];
    #pragma unroll
    for (int n = 0; n < 4; ++n) {
        int gc = C0 + wc * 64 + n * 16 + lsub;
        lc4[n] = labels[gc];
        sc4[n] = sq[gc];
    }
    const float INF = __int_as_float(0x7f800000);
    float hpc[4], hnc[4];
    #pragma unroll
    for (int n = 0; n < 4; ++n) { hpc[n] = 0.f; hnc[n] = INF; }

    #pragma unroll
    for (int m = 0; m < 4; ++m) {
        int growb = R0 + wr * 64 + m * 16 + (lgrp << 2);
        #pragma unroll
        for (int j = 0; j < 4; ++j) {
            int grow = growb + j;
            int lr = labels[grow];
            float sr = sq[grow];
            float hp = 0.f, hn = INF;
            #pragma unroll
            for (int n = 0; n < 4; ++n) {
                float d2 = fmaf(-2.f, acc[m][n][j], sr + sc4[n]);
                d2 = fmaxf(d2, 0.f);
                bool same = (lr == lc4[n]);
                hp = same ? fmaxf(hp, d2) : hp;
                hn = same ? hn : fminf(hn, d2);
                hpc[n] = same ? fmaxf(hpc[n], d2) : hpc[n];   // col anchors
                hnc[n] = same ? hnc[n] : fminf(hnc[n], d2);
            }
            #pragma unroll
            for (int s = 1; s < 16; s <<= 1) {    // reduce 16 col-lanes
                hp = fmaxf(hp, __shfl_xor(hp, s, 64));
                hn = fminf(hn, __shfl_xor(hn, s, 64));
            }
            if (lsub == 0) {
                // d2 >= 0 -> float order == signed-int bit order
                atomicMax(reinterpret_cast<int*>(hp2) + grow, __float_as_int(hp));
                atomicMin(reinterpret_cast<int*>(hn2) + grow, __float_as_int(hn));
            }
        }
    }
    // col-anchor reduce across the 4 row-groups (lanes l, l^16, l^32, l^48)
    #pragma unroll
    for (int n = 0; n < 4; ++n) {
        float p = hpc[n], q = hnc[n];
        p = fmaxf(p, __shfl_xor(p, 16, 64));
        q = fminf(q, __shfl_xor(q, 16, 64));
        p = fmaxf(p, __shfl_xor(p, 32, 64));
        q = fminf(q, __shfl_xor(q, 32, 64));
        if (l < 16) {
            int gc = C0 + wc * 64 + n * 16 + l;
            atomicMax(reinterpret_cast<int*>(hp2) + gc, __float_as_int(p));
            atomicMin(reinterpret_cast<int*>(hn2) + gc, __float_as_int(q));
        }
    }
}

// ------------------------------------------------------------ finalize ----
__global__ void finalize_kernel(const unsigned* __restrict__ hp2,
                                const unsigned* __restrict__ hn2,
                                const int* __restrict__ labels,
                                float* __restrict__ out) {
    __shared__ int hist[64];
    __shared__ float ss[4], cc[4];
    if (threadIdx.x < 64) hist[threadIdx.x] = 0;
    __syncthreads();
    for (int i = threadIdx.x; i < N_PTS; i += 256)
        atomicAdd(&hist[labels[i]], 1);
    __syncthreads();

    float s = 0.f, c = 0.f;
    for (int i = threadIdx.x; i < N_PTS; i += 256) {
        float hp = __uint_as_float(hp2[i]);
        float hn = __uint_as_float(hn2[i]);
        int h = hist[labels[i]];
        bool valid = (h > 1) && (h < N_PTS) && (hp > 0.f) && (hn < 3.0e38f);
        if (valid) {
            s += fmaxf(sqrtf(hp) - sqrtf(hn) + MARGIN, 0.f);
            c += 1.f;
        }
    }
    #pragma unroll
    for (int m = 1; m < 64; m <<= 1) {
        s += __shfl_xor(s, m, 64);
        c += __shfl_xor(c, m, 64);
    }
    int w = threadIdx.x >> 6, lv = threadIdx.x & 63;
    if (lv == 0) { ss[w] = s; cc[w] = c; }
    __syncthreads();
    if (threadIdx.x == 0) {
        float S = ss[0] + ss[1] + ss[2] + ss[3];
        float C = cc[0] + cc[1] + cc[2] + cc[3];
        out[0] = (C > 0.f) ? (S / C) : 0.f;
    }
}

// -------------------------------------------------------------- launch ----
extern "C" void kernel_launch(void* const* d_in, const int* in_sizes, int n_in,
                              void* d_out, int out_size, void* d_ws, size_t ws_size,
                              hipStream_t stream) {
    const float* X      = (const float*)d_in[0];
    const int*   labels = (const int*)d_in[1];
    float*       out    = (float*)d_out;

    char* ws = (char*)d_ws;
    unsigned short* Xb = (unsigned short*)ws;                       // 4 MB
    float*    sq  = (float*)(ws + (size_t)N_PTS * DIM * 2);
    unsigned* hp2 = (unsigned*)((char*)sq  + N_PTS * sizeof(float));
    unsigned* hn2 = (unsigned*)((char*)hp2 + N_PTS * sizeof(unsigned));

    prep_kernel<<<N_PTS / 4, 256, 0, stream>>>(X, Xb, sq, hp2, hn2);
    mine_kernel<<<NPAIR, 256, 0, stream>>>(Xb, sq, labels, hp2, hn2);
    finalize_kernel<<<1, 256, 0, stream>>>(hp2, hn2, labels, out);
}